// Round 7
// baseline (183.482 us; speedup 1.0000x reference)
//
#include <hip/hip_runtime.h>
#include <hip/hip_bf16.h>
#include <stdint.h>

// out[b,s,d] = sum_t w[b,s,t] * x[b,t,d]
//   w = softmax(uniform(key=42, (4,4096,4096), -0.1, 0.1), -1) / denom,
//   denom[s] = sum_{b,t} softmax = 4 exactly (softmax rows sum to 1).
// PRNG: JAX partitionable threefry (verified round 2): counter (0, flat_idx),
// key (0,42), draw = x0 ^ x1; bits -> [1,2) -> [0,1) -> [-0.1, 0.1).
// GEMM on MFMA bf16 16x16x32. W and X^T both stored [row][k] in LDS and loaded
// with the SAME k-contiguous lane mapping, so any HW k-permutation cancels.

#define S_ 4096
#define D_ 64
#define TK 64
#define TS 16
#define LDK 72   // LDS k-stride (bf16 elems): 144B rows -> 2-way banks, 16B aligned

typedef __attribute__((ext_vector_type(8))) short short8v;   // 8 bf16 = 4 VGPR
typedef __attribute__((ext_vector_type(4))) short short4v;   // 8B
typedef __attribute__((ext_vector_type(4))) float floatx4;

__device__ __forceinline__ uint32_t rotl32(uint32_t x, unsigned r) {
    return (x << r) | (x >> (32u - r));
}

// Partitionable-threefry 32-bit draw for counter (0, f), key (0, 42). (verified)
__device__ __forceinline__ uint32_t threefry_bits(uint32_t f) {
    const uint32_t k0 = 0u, k1 = 42u;
    const uint32_t k2 = 0x1BD11BDAu ^ k0 ^ k1;
    uint32_t x0 = k0;
    uint32_t x1 = f + k1;
#define TFR(r) { x0 += x1; x1 = rotl32(x1, (r)); x1 ^= x0; }
    TFR(13) TFR(15) TFR(26) TFR(6)
    x0 += k1; x1 += k2 + 1u;
    TFR(17) TFR(29) TFR(16) TFR(24)
    x0 += k2; x1 += k0 + 2u;
    TFR(13) TFR(15) TFR(26) TFR(6)
    x0 += k0; x1 += k1 + 3u;
    TFR(17) TFR(29) TFR(16) TFR(24)
    x0 += k1; x1 += k2 + 4u;
    TFR(13) TFR(15) TFR(26) TFR(6)
    x0 += k2; x1 += k0 + 5u;
#undef TFR
    return x0 ^ x1;
}

__device__ __forceinline__ float uniform_exp(uint32_t bits) {
    uint32_t fb = (bits >> 9) | 0x3F800000u;
    float f = __uint_as_float(fb) - 1.0f;
    float u = fmaxf(-0.1f, fmaf(f, 0.2f, -0.1f));
    return __expf(u);
}

__device__ __forceinline__ short f2bf(float v) {
    __hip_bfloat16 h = __float2bfloat16(v);   // RNE hw convert
    return __builtin_bit_cast(short, h);
}

__global__ __launch_bounds__(256, 4) void fused_rand_attn_mfma(
    const float* __restrict__ x, float* __restrict__ out)
{
    const int tid = threadIdx.x;
    // XCD-aware swizzle: 1024 blocks, 8 XCDs -> each XCD owns a contiguous
    // 128-tile chunk (single batch half) => per-XCD X working set 1MB, L2-fits.
    const int bid = (blockIdx.x & 7) * 128 + (blockIdx.x >> 3);
    const int b   = bid >> 8;            // batch 0..3
    const int s0  = (bid & 255) * TS;    // row-tile start

    __shared__ short Wl[2][TS][LDK];     // A tiles (bf16), double-buffered
    __shared__ short XTl[2][D_][LDK];    // B tiles = X^T (bf16), double-buffered
    __shared__ float Zl[TS][17];
    __shared__ float Zf[TS];

    const int lane = tid & 63;
    const int w    = tid >> 6;           // wave id 0..3 -> owns d-cols 16w..16w+15
    const int sl   = tid & 15;           // PRNG row (fixed per thread)
    const int kg   = tid >> 4;           // PRNG k-subindex 0..15
    const int kk   = (tid & 15) * 4;     // X staging: k-base (4 rows)
    const int dd   = (tid >> 4) * 4;     // X staging: d-base (4 cols)
    const int lt   = lane & 15;
    const int lh   = lane >> 4;

    floatx4 acc = {0.f, 0.f, 0.f, 0.f};
    float zpart = 0.0f;

    const float* __restrict__ xb = x + (size_t)b * (S_ * D_);
    const uint32_t fbase = ((uint32_t)b << 24) + ((uint32_t)(s0 + sl) << 12);

    for (int kt = 0; kt < S_ / TK; ++kt) {
        const int k0  = kt << 6;
        const int buf = kt & 1;

        // ---- issue X staging loads early (latency hides under PRNG) ----
        union { floatx4 v; float f[4]; } xr[4];
#pragma unroll
        for (int i = 0; i < 4; ++i)
            xr[i].v = *(const floatx4*)&xb[(size_t)(k0 + kk + i) * D_ + dd];

        // ---- W generation: 4 draws, row sl, cols kl = p*16+kg ----
        float ev[4];
#pragma unroll
        for (int p = 0; p < 4; ++p) {
            const uint32_t f = fbase + (uint32_t)(k0 + p * 16 + kg);
            ev[p] = uniform_exp(threefry_bits(f));
            zpart += ev[p];               // fp32 row-sum (exact softmax denom)
        }
#pragma unroll
        for (int p = 0; p < 4; ++p)
            Wl[buf][sl][p * 16 + kg] = f2bf(ev[p]);

        // ---- transpose-stage X tile to bf16 LDS: XTl[d][k] ----
#pragma unroll
        for (int j = 0; j < 4; ++j) {
            short4v v4 = { f2bf(xr[0].f[j]), f2bf(xr[1].f[j]),
                           f2bf(xr[2].f[j]), f2bf(xr[3].f[j]) };
            *(short4v*)&XTl[buf][dd + j][kk] = v4;
        }

        __syncthreads();   // gen(buf) complete; reads(buf) below; next iter
                           // writes buf^1, so one barrier per kt suffices.

        // ---- MFMA: A = W[16s x 64k], B = X^T[16d x 64k], 2 k-chunks ----
#pragma unroll
        for (int kc = 0; kc < 2; ++kc) {
            const int ko = kc * 32 + 8 * lh;   // same k mapping for A and B
            short8v a  = *(const short8v*)&Wl[buf][lt][ko];
            short8v bv = *(const short8v*)&XTl[buf][w * 16 + lt][ko];
            acc = __builtin_amdgcn_mfma_f32_16x16x32_bf16(a, bv, acc, 0, 0, 0);
        }
    }

    // ---- Z reduction ----
    Zl[sl][kg] = zpart;
    __syncthreads();
    if (tid < TS) {
        float z = 0.f;
#pragma unroll
        for (int c = 0; c < 16; ++c) z += Zl[tid][c];
        Zf[tid] = z;
    }
    __syncthreads();

    // ---- epilogue: C layout col=lane&15 (d), row=(lane>>4)*4+reg (s) ----
    const int n = w * 16 + lt;
#pragma unroll
    for (int r = 0; r < 4; ++r) {
        const int row = lh * 4 + r;
        const float scale = 1.0f / (4.0f * Zf[row]);
        out[((size_t)b * S_ + (s0 + row)) * D_ + n] = acc[r] * scale;
    }
}

extern "C" void kernel_launch(void* const* d_in, const int* in_sizes, int n_in,
                              void* d_out, int out_size, void* d_ws, size_t ws_size,
                              hipStream_t stream) {
    const float* x = (const float*)d_in[0];   // [4,4096,64] fp32
    // d_in[1] (attn_mask) is dead in the reference; unused.
    float* out = (float*)d_out;               // [4,4096,64] fp32
    (void)d_ws; (void)ws_size; (void)in_sizes; (void)n_in; (void)out_size;
    // 4 batches x 256 row-tiles of 16 = 1024 blocks, 256 threads (4 waves)
    hipLaunchKernelGGL(fused_rand_attn_mfma, dim3(1024), dim3(256), 0, stream,
                       x, out);
}

// Round 8
// 141.845 us; speedup vs baseline: 1.2935x; 1.2935x over previous
//
#include <hip/hip_runtime.h>
#include <hip/hip_bf16.h>
#include <stdint.h>

// out[b,s,d] = sum_t w[b,s,t] * x[b,t,d]
//   w = softmax(uniform(key=42, (4,4096,4096), -0.1, 0.1), -1) / 4   (denom
//   = sum_{b,t} softmax = B = 4 exactly; verified rounds 2-7).
// PRNG (verified round 2): JAX partitionable threefry, counter (0, flat_idx),
// key (0,42), draw = x0 ^ x1.
// Round 8 structure: prologue packs X^T bf16 into MFMA B-fragment lane order
// (d_ws, 2MB, L2-resident). Main kernel: each wave generates its A-fragment
// (W rows) straight into registers -- no W LDS round trip, no X staging, no
// barriers in the main loop. Block = one 16-row s-tile; 4 waves split k-tiles
// round-robin and merge partial acc/Z once at the end.

#define S_ 4096
#define D_ 64

typedef __attribute__((ext_vector_type(8))) short short8v;   // 8 bf16 = 4 VGPR
typedef __attribute__((ext_vector_type(4))) float floatx4;

__device__ __forceinline__ uint32_t rotl32(uint32_t x, unsigned r) {
    return (x << r) | (x >> (32u - r));   // -> v_alignbit_b32
}

// Partitionable-threefry 32-bit draw for counter (0, f), key (0, 42). (verified)
__device__ __forceinline__ uint32_t threefry_bits(uint32_t f) {
    const uint32_t k0 = 0u, k1 = 42u;
    const uint32_t k2 = 0x1BD11BDAu ^ k0 ^ k1;
    uint32_t x0 = k0;
    uint32_t x1 = f + k1;
#define TFR(r) { x0 += x1; x1 = rotl32(x1, (r)); x1 ^= x0; }
    TFR(13) TFR(15) TFR(26) TFR(6)
    x0 += k1; x1 += k2 + 1u;
    TFR(17) TFR(29) TFR(16) TFR(24)
    x0 += k2; x1 += k0 + 2u;
    TFR(13) TFR(15) TFR(26) TFR(6)
    x0 += k0; x1 += k1 + 3u;
    TFR(17) TFR(29) TFR(16) TFR(24)
    x0 += k1; x1 += k2 + 4u;
    TFR(13) TFR(15) TFR(26) TFR(6)
    x0 += k2; x1 += k0 + 5u;
#undef TFR
    return x0 ^ x1;
}

// exp(u), u = 0.2*t - 0.3, t = 1.f | mantissa(bits) in [1,2).
// Cubic Taylor: |rel err| < 5e-6 over [-0.1, 0.1) -- 500x under bf16 rounding.
// (Reference's max(-0.1, .) clamp is dead: u >= -0.1 - 1e-8 always.)
__device__ __forceinline__ float uniform_exp_poly(uint32_t bits) {
    const float t = __uint_as_float((bits >> 9) | 0x3F800000u);
    const float u = __builtin_fmaf(t, 0.2f, -0.3f);
    float p = __builtin_fmaf(u, 0.16666667f, 0.5f);
    p = __builtin_fmaf(p, u, 1.0f);
    return __builtin_fmaf(p, u, 1.0f);
}

// ---- prologue: pack X^T (bf16) in B-fragment lane order ----
// bf[((b*4+dg)*128+kc)*512 + l*8 + j] = bf16( X[b][kc*32+(l>>4)*8+j][dg*16+(l&15)] )
__global__ __launch_bounds__(64) void pack_xt_bf16(
    const float* __restrict__ x, short* __restrict__ bf)
{
    const int id = blockIdx.x;            // (b<<9)|(dg<<7)|kc, 2048 blocks
    const int l  = threadIdx.x;           // 0..63
    const int kc = id & 127;
    const int dg = (id >> 7) & 3;
    const int b  = id >> 9;
    const int d  = dg * 16 + (l & 15);
    const int k0 = kc * 32 + (l >> 4) * 8;
    const float* __restrict__ xb = x + (size_t)b * (S_ * D_);
    union { short8v v; short s[8]; } r;
#pragma unroll
    for (int j = 0; j < 8; ++j) {
        __hip_bfloat16 h = __float2bfloat16(xb[(size_t)(k0 + j) * D_ + d]);
        r.s[j] = __builtin_bit_cast(short, h);
    }
    *(short8v*)&bf[(size_t)id * 512 + l * 8] = r.v;
}

__global__ __launch_bounds__(256, 4) void fused_rand_attn_mfma2(
    const short* __restrict__ bf, float* __restrict__ out)
{
    const int tid  = threadIdx.x;
    // XCD-aware swizzle (1024 % 8 == 0 -> bijective)
    const int bid  = (blockIdx.x & 7) * 128 + (blockIdx.x >> 3);
    const int b    = bid >> 8;            // batch
    const int s0   = (bid & 255) * 16;    // s-tile start
    const int w    = tid >> 6;            // wave 0..3: k-tiles kt = w, w+4, ...
    const int lane = tid & 63;
    const int lt   = lane & 15;
    const int lh   = lane >> 4;

    __shared__ float ACC[4][4][64][4];    // [wave][dgroup][lane][reg]  16 KiB
    __shared__ float ZL[4][16];           // [wave][row]

    floatx4 acc0 = {0.f,0.f,0.f,0.f}, acc1 = {0.f,0.f,0.f,0.f};
    floatx4 acc2 = {0.f,0.f,0.f,0.f}, acc3 = {0.f,0.f,0.f,0.f};
    float zp = 0.f;

    const short* __restrict__ bfb = bf + (size_t)b * (4 * 128 * 512);
    const uint32_t fbase = ((uint32_t)b << 24) | ((uint32_t)(s0 + lt) << 12);

#pragma unroll 1                           // keep body ~10KB, fits I-cache
    for (int kt = w; kt < 64; kt += 4) {
        // ---- B fragments: coalesced 1KB/load, L2-resident, no conversion ----
        short8v bfr[8];
#pragma unroll
        for (int dg = 0; dg < 4; ++dg)
#pragma unroll
            for (int kc = 0; kc < 2; ++kc)
                bfr[dg * 2 + kc] = *(const short8v*)
                    &bfb[(size_t)((dg * 128 + kt * 2 + kc) * 512 + lane * 8)];

        // ---- A fragments: 16 threefry draws -> poly exp -> bf16 pack ----
        union { uint32_t u[4]; short8v v; } a0, a1;
#pragma unroll
        for (int kc = 0; kc < 2; ++kc) {
            const uint32_t kb = fbase + (uint32_t)(kt * 64 + kc * 32 + lh * 8);
#pragma unroll
            for (int jp = 0; jp < 4; ++jp) {
                const float e0 = uniform_exp_poly(threefry_bits(kb + 2 * jp));
                const float e1 = uniform_exp_poly(threefry_bits(kb + 2 * jp + 1));
                zp += e0 + e1;            // exact fp32 softmax denom
                const uint32_t u0 = __float_as_uint(e0) + 0x8000u;
                const uint32_t u1 = __float_as_uint(e1) + 0x8000u;
                const uint32_t pk = (u0 >> 16) | (u1 & 0xFFFF0000u);
                if (kc == 0) a0.u[jp] = pk; else a1.u[jp] = pk;
            }
        }

        // ---- 8 MFMA: acc[dg] += A(16s x 32k) . B(16d x 32k)^T, 2 k-chunks ----
        acc0 = __builtin_amdgcn_mfma_f32_16x16x32_bf16(a0.v, bfr[0], acc0, 0,0,0);
        acc0 = __builtin_amdgcn_mfma_f32_16x16x32_bf16(a1.v, bfr[1], acc0, 0,0,0);
        acc1 = __builtin_amdgcn_mfma_f32_16x16x32_bf16(a0.v, bfr[2], acc1, 0,0,0);
        acc1 = __builtin_amdgcn_mfma_f32_16x16x32_bf16(a1.v, bfr[3], acc1, 0,0,0);
        acc2 = __builtin_amdgcn_mfma_f32_16x16x32_bf16(a0.v, bfr[4], acc2, 0,0,0);
        acc2 = __builtin_amdgcn_mfma_f32_16x16x32_bf16(a1.v, bfr[5], acc2, 0,0,0);
        acc3 = __builtin_amdgcn_mfma_f32_16x16x32_bf16(a0.v, bfr[6], acc3, 0,0,0);
        acc3 = __builtin_amdgcn_mfma_f32_16x16x32_bf16(a1.v, bfr[7], acc3, 0,0,0);
    }

    // ---- merge partial Z (this wave's k-tiles) across lh groups ----
    zp += __shfl_xor(zp, 16);
    zp += __shfl_xor(zp, 32);
    if (lane < 16) ZL[w][lane] = zp;
    *(floatx4*)&ACC[w][0][lane][0] = acc0;
    *(floatx4*)&ACC[w][1][lane][0] = acc1;
    *(floatx4*)&ACC[w][2][lane][0] = acc2;
    *(floatx4*)&ACC[w][3][lane][0] = acc3;
    __syncthreads();                      // the only barrier in the kernel

    // ---- wave w finalizes d-group w: sum 4 wave-partials, scale, store ----
    floatx4 facc = {0.f,0.f,0.f,0.f};
#pragma unroll
    for (int w2 = 0; w2 < 4; ++w2) {
        const floatx4 t = *(const floatx4*)&ACC[w2][w][lane][0];
        facc.x += t.x; facc.y += t.y; facc.z += t.z; facc.w += t.w;
    }
    const int col = w * 16 + lt;
#pragma unroll
    for (int r = 0; r < 4; ++r) {
        const int row = lh * 4 + r;       // C layout: col=lane&15, row=lh*4+reg
        const float Z = ZL[0][row] + ZL[1][row] + ZL[2][row] + ZL[3][row];
        const float scale = 1.0f / (4.0f * Z);
        out[((size_t)b * S_ + (s0 + row)) * D_ + col] = facc[r] * scale;
    }
}

extern "C" void kernel_launch(void* const* d_in, const int* in_sizes, int n_in,
                              void* d_out, int out_size, void* d_ws, size_t ws_size,
                              hipStream_t stream) {
    const float* x = (const float*)d_in[0];   // [4,4096,64] fp32
    // d_in[1] (attn_mask) is dead in the reference; unused.
    float* out = (float*)d_out;               // [4,4096,64] fp32
    short* bfw = (short*)d_ws;                // needs 2 MiB scratch
    (void)in_sizes; (void)n_in; (void)out_size; (void)ws_size;
    // prologue: one-time X^T bf16 fragment pack (same stream -> ordered)
    hipLaunchKernelGGL(pack_xt_bf16, dim3(2048), dim3(64), 0, stream, x, bfw);
    // main: 4 batches x 256 s-tiles = 1024 blocks x 4 waves
    hipLaunchKernelGGL(fused_rand_attn_mfma2, dim3(1024), dim3(256), 0, stream,
                       bfw, out);
}

// Round 9
// 133.212 us; speedup vs baseline: 1.3774x; 1.0648x over previous
//
#include <hip/hip_runtime.h>
#include <hip/hip_bf16.h>
#include <stdint.h>

// out[b,s,d] = sum_t w[b,s,t] * x[b,t,d]
//   w = softmax(uniform(key=42, (4,4096,4096), -0.1, 0.1), -1) / 4   (denom
//   = sum_{b,t} softmax = B = 4 exactly; verified rounds 2-8).
// PRNG (verified): JAX partitionable threefry, counter (0, flat_idx),
// key (0,42), draw = x0 ^ x1.
// Round 9: latency-bound fix. 8 waves/block (512 thr) -> up to 32 waves/CU
// (was grid-capped at 16). B loads split per k-chunk to overlap MFMA+PRNG.
// v_cvt_pk_bf16_f32 pack (1 op vs 5). Two independent zp chains.

#define S_ 4096
#define D_ 64

typedef __attribute__((ext_vector_type(8))) short short8v;   // 8 bf16 = 4 VGPR
typedef __attribute__((ext_vector_type(4))) float floatx4;

__device__ __forceinline__ uint32_t rotl32(uint32_t x, unsigned r) {
    return (x << r) | (x >> (32u - r));   // -> v_alignbit_b32
}

// Partitionable-threefry 32-bit draw for counter (0, f), key (0, 42). (verified)
__device__ __forceinline__ uint32_t threefry_bits(uint32_t f) {
    const uint32_t k0 = 0u, k1 = 42u;
    const uint32_t k2 = 0x1BD11BDAu ^ k0 ^ k1;
    uint32_t x0 = k0;
    uint32_t x1 = f + k1;
#define TFR(r) { x0 += x1; x1 = rotl32(x1, (r)); x1 ^= x0; }
    TFR(13) TFR(15) TFR(26) TFR(6)
    x0 += k1; x1 += k2 + 1u;
    TFR(17) TFR(29) TFR(16) TFR(24)
    x0 += k2; x1 += k0 + 2u;
    TFR(13) TFR(15) TFR(26) TFR(6)
    x0 += k0; x1 += k1 + 3u;
    TFR(17) TFR(29) TFR(16) TFR(24)
    x0 += k1; x1 += k2 + 4u;
    TFR(13) TFR(15) TFR(26) TFR(6)
    x0 += k2; x1 += k0 + 5u;
#undef TFR
    return x0 ^ x1;
}

// exp(u), u = 0.2*t - 0.3, t in [1,2). Cubic Taylor, |rel err| < 5e-6.
__device__ __forceinline__ float uniform_exp_poly(uint32_t bits) {
    const float t = __uint_as_float((bits >> 9) | 0x3F800000u);
    const float u = __builtin_fmaf(t, 0.2f, -0.3f);
    float p = __builtin_fmaf(u, 0.16666667f, 0.5f);
    p = __builtin_fmaf(p, u, 1.0f);
    return __builtin_fmaf(p, u, 1.0f);
}

// packed pair {lo: bf16(e0), hi: bf16(e1)}, RNE, single instruction
__device__ __forceinline__ uint32_t cvt_pk_bf16(float e0, float e1) {
    uint32_t r;
    asm("v_cvt_pk_bf16_f32 %0, %1, %2" : "=v"(r) : "v"(e0), "v"(e1));
    return r;
}

// 8 consecutive exp-weights (counters c0..c0+7) -> bf16x8 A-fragment regs
__device__ __forceinline__ short8v gen_a(uint32_t c0, float& zpA, float& zpB) {
    union { uint32_t u[4]; short8v v; } a;
#pragma unroll
    for (int jp = 0; jp < 4; ++jp) {
        const float e0 = uniform_exp_poly(threefry_bits(c0 + 2u * jp));
        const float e1 = uniform_exp_poly(threefry_bits(c0 + 2u * jp + 1u));
        zpA += e0;          // two independent accumulation chains
        zpB += e1;
        a.u[jp] = cvt_pk_bf16(e0, e1);
    }
    return a.v;
}

// ---- prologue: pack X^T (bf16) in B-fragment lane order (unchanged) ----
// bf[((b*4+dg)*128+kc)*512 + l*8 + j] = bf16( X[b][kc*32+(l>>4)*8+j][dg*16+(l&15)] )
__global__ __launch_bounds__(64) void pack_xt_bf16(
    const float* __restrict__ x, short* __restrict__ bf)
{
    const int id = blockIdx.x;            // (b<<9)|(dg<<7)|kc, 2048 blocks
    const int l  = threadIdx.x;           // 0..63
    const int kc = id & 127;
    const int dg = (id >> 7) & 3;
    const int b  = id >> 9;
    const int d  = dg * 16 + (l & 15);
    const int k0 = kc * 32 + (l >> 4) * 8;
    const float* __restrict__ xb = x + (size_t)b * (S_ * D_);
    union { short8v v; short s[8]; } r;
#pragma unroll
    for (int j = 0; j < 8; ++j) {
        __hip_bfloat16 h = __float2bfloat16(xb[(size_t)(k0 + j) * D_ + d]);
        r.s[j] = __builtin_bit_cast(short, h);
    }
    *(short8v*)&bf[(size_t)id * 512 + l * 8] = r.v;
}

__global__ __launch_bounds__(512, 6) void fused_rand_attn_mfma3(
    const short* __restrict__ bf, float* __restrict__ out)
{
    const int tid  = threadIdx.x;
    // XCD-aware swizzle (1024 % 8 == 0 -> bijective)
    const int bid  = (blockIdx.x & 7) * 128 + (blockIdx.x >> 3);
    const int b    = bid >> 8;            // batch
    const int s0   = (bid & 255) * 16;    // s-tile start
    const int w    = tid >> 6;            // wave 0..7: k-tiles kt = w, w+8, ...
    const int lane = tid & 63;
    const int lt   = lane & 15;
    const int lh   = lane >> 4;

    __shared__ float ACC[8][4][64][4];    // [wave][dgroup][lane][reg]  32 KiB
    __shared__ float ZL[8][16];           // [wave][row]

    floatx4 acc0 = {0.f,0.f,0.f,0.f}, acc1 = {0.f,0.f,0.f,0.f};
    floatx4 acc2 = {0.f,0.f,0.f,0.f}, acc3 = {0.f,0.f,0.f,0.f};
    float zpA = 0.f, zpB = 0.f;

    const short* __restrict__ bl =
        bf + (size_t)b * (4 * 128 * 512) + (size_t)lane * 8;
    const uint32_t fl = (((uint32_t)b << 24) | ((uint32_t)(s0 + lt) << 12))
                        + (uint32_t)(lh * 8);

#pragma unroll 1
    for (int kt = w; kt < 64; kt += 8) {
        const short* pk = bl + (size_t)kt * 1024;
        const uint32_t kb = fl + ((uint32_t)kt << 6);

        // kc=0 B fragments (4 x dwordx4, coalesced, L2-resident)
        const short8v b00 = *(const short8v*)(pk);
        const short8v b10 = *(const short8v*)(pk + 65536);
        const short8v b20 = *(const short8v*)(pk + 131072);
        const short8v b30 = *(const short8v*)(pk + 196608);

        // A fragment kc=0: 8 threefry chains (loads above in flight)
        const short8v a0 = gen_a(kb, zpA, zpB);

        // kc=1 B fragments: in flight across 4 MFMAs + next gen
        const short8v b01 = *(const short8v*)(pk + 512);
        const short8v b11 = *(const short8v*)(pk + 65536 + 512);
        const short8v b21 = *(const short8v*)(pk + 131072 + 512);
        const short8v b31 = *(const short8v*)(pk + 196608 + 512);

        acc0 = __builtin_amdgcn_mfma_f32_16x16x32_bf16(a0, b00, acc0, 0, 0, 0);
        acc1 = __builtin_amdgcn_mfma_f32_16x16x32_bf16(a0, b10, acc1, 0, 0, 0);
        acc2 = __builtin_amdgcn_mfma_f32_16x16x32_bf16(a0, b20, acc2, 0, 0, 0);
        acc3 = __builtin_amdgcn_mfma_f32_16x16x32_bf16(a0, b30, acc3, 0, 0, 0);

        const short8v a1 = gen_a(kb + 32u, zpA, zpB);

        acc0 = __builtin_amdgcn_mfma_f32_16x16x32_bf16(a1, b01, acc0, 0, 0, 0);
        acc1 = __builtin_amdgcn_mfma_f32_16x16x32_bf16(a1, b11, acc1, 0, 0, 0);
        acc2 = __builtin_amdgcn_mfma_f32_16x16x32_bf16(a1, b21, acc2, 0, 0, 0);
        acc3 = __builtin_amdgcn_mfma_f32_16x16x32_bf16(a1, b31, acc3, 0, 0, 0);
    }

    // ---- merge this wave's Z partial across lh groups ----
    float zp = zpA + zpB;
    zp += __shfl_xor(zp, 16);
    zp += __shfl_xor(zp, 32);
    if (lane < 16) ZL[w][lane] = zp;
    *(floatx4*)&ACC[w][0][lane][0] = acc0;
    *(floatx4*)&ACC[w][1][lane][0] = acc1;
    *(floatx4*)&ACC[w][2][lane][0] = acc2;
    *(floatx4*)&ACC[w][3][lane][0] = acc3;
    __syncthreads();                      // the only barrier in the kernel

    // ---- wave w: d-group w&3, row-half w>>2 (2 rows/thread) ----
    const int dg = w & 3;
    const int rh = w >> 2;
    floatx4 facc = {0.f,0.f,0.f,0.f};
#pragma unroll
    for (int w2 = 0; w2 < 8; ++w2) {
        const floatx4 t = *(const floatx4*)&ACC[w2][dg][lane][0];
        facc.x += t.x; facc.y += t.y; facc.z += t.z; facc.w += t.w;
    }
    // static selects (no dynamic vector index -> no scratch)
    const float v0 = rh ? facc.z : facc.x;
    const float v1 = rh ? facc.w : facc.y;
    const int row0 = lh * 4 + rh * 2;     // C layout: col=lane&15, row=lh*4+reg
    float Z0 = 0.f, Z1 = 0.f;
#pragma unroll
    for (int w2 = 0; w2 < 8; ++w2) {
        Z0 += ZL[w2][row0];
        Z1 += ZL[w2][row0 + 1];
    }
    const int col = dg * 16 + lt;
    out[((size_t)b * S_ + (s0 + row0)) * D_ + col]     = v0 * (0.25f / Z0);
    out[((size_t)b * S_ + (s0 + row0 + 1)) * D_ + col] = v1 * (0.25f / Z1);
}

extern "C" void kernel_launch(void* const* d_in, const int* in_sizes, int n_in,
                              void* d_out, int out_size, void* d_ws, size_t ws_size,
                              hipStream_t stream) {
    const float* x = (const float*)d_in[0];   // [4,4096,64] fp32
    // d_in[1] (attn_mask) is dead in the reference; unused.
    float* out = (float*)d_out;               // [4,4096,64] fp32
    short* bfw = (short*)d_ws;                // 2 MiB scratch
    (void)in_sizes; (void)n_in; (void)out_size; (void)ws_size;
    // prologue: one-time X^T bf16 fragment pack (same stream -> ordered)
    hipLaunchKernelGGL(pack_xt_bf16, dim3(2048), dim3(64), 0, stream, x, bfw);
    // main: 4 batches x 256 s-tiles = 1024 blocks x 8 waves (512 threads)
    hipLaunchKernelGGL(fused_rand_attn_mfma3, dim3(1024), dim3(512), 0, stream,
                       bfw, out);
}